// Round 1
// baseline (11878.555 us; speedup 1.0000x reference)
//
#include <hip/hip_runtime.h>

typedef unsigned int u32;
typedef _Float16 f16x2 __attribute__((ext_vector_type(2)));

#define TP 600
#define TQ 60
#define BB 64
#define EMB 344
#define HH 256
#define H2 128
#define GG 512

// ---------- fast math helpers ----------
__device__ __forceinline__ float exp2_fast(float x){
#if __has_builtin(__builtin_amdgcn_exp2f)
    return __builtin_amdgcn_exp2f(x);
#else
    return exp2f(x);
#endif
}
__device__ __forceinline__ float rcp_fast(float x){
#if __has_builtin(__builtin_amdgcn_rcpf)
    return __builtin_amdgcn_rcpf(x);
#else
    return 1.0f / x;
#endif
}
__device__ __forceinline__ float sigm_fast(float x){
    return rcp_fast(1.f + exp2_fast(-1.44269504f * x));
}
__device__ __forceinline__ float tanh_fast(float x){
    // tanh(x) = 1 - 2/(1+e^{2x}) ; e^{2x} = 2^{x*2*log2(e)}
    return 1.f - 2.f * rcp_fast(1.f + exp2_fast(2.88539008f * x));
}
// packed-half2 dot into fp32 acc (compiler emits v_fma_mix)
__device__ __forceinline__ float dot2x(u32 w, u32 h, float acc){
    f16x2 wv = __builtin_bit_cast(f16x2, w);
    f16x2 hv = __builtin_bit_cast(f16x2, h);
    acc = fmaf((float)wv.x, (float)hv.x, acc);
    acc = fmaf((float)wv.y, (float)hv.y, acc);
    return acc;
}
__device__ __forceinline__ u32 pack2(float a, float b){
    f16x2 v; v.x = (_Float16)a; v.y = (_Float16)b;
    return __builtin_bit_cast(u32, v);
}

// ---------- prep: transpose weights (fp32 WT4 layout) + fp16 packing ----------
__global__ void prep_kernel(const float* __restrict__ pre0_Wih, const float* __restrict__ pre0_Whh,
                            const float* __restrict__ pre1_Wih, const float* __restrict__ pre1_Whh,
                            const float* __restrict__ Wq, const float* __restrict__ Wp,
                            const float* __restrict__ Whm, const float* __restrict__ Wihm,
                            const float* __restrict__ Whhm,
                            float* __restrict__ WT0, float* __restrict__ WT1,
                            float* __restrict__ WTq, float* __restrict__ WTp,
                            float* __restrict__ WTz,
                            u32* __restrict__ P0hh, u32* __restrict__ P1hh,
                            u32* __restrict__ PMhh, u32* __restrict__ PMwh,
                            uint4* __restrict__ PMwq)
{
    int g = blockIdx.x * blockDim.x + threadIdx.x;
    int gs = gridDim.x * blockDim.x;
    // WT0: pre0_Wih [512][344] -> [k/4][512][4]
    for (int idx = g; idx < 512*344; idx += gs) {
        int j = idx / 344, k = idx - j*344;
        WT0[((k>>2)*512 + j)*4 + (k&3)] = pre0_Wih[idx];
    }
    // WT1: pre1_Wih [512][256]
    for (int idx = g; idx < 512*256; idx += gs) {
        int j = idx >> 8, k = idx & 255;
        WT1[((k>>2)*512 + j)*4 + (k&3)] = pre1_Wih[idx];
    }
    // WTq / WTp: [256][256]
    for (int idx = g; idx < 256*256; idx += gs) {
        int j = idx >> 8, k = idx & 255;
        WTq[((k>>2)*256 + j)*4 + (k&3)] = Wq[idx];
        WTp[((k>>2)*256 + j)*4 + (k&3)] = Wp[idx];
    }
    // WTz: mq_Wih[:, 0:256] ([512 rows][512 cols], cols 0..255)
    for (int idx = g; idx < 512*256; idx += gs) {
        int j = idx >> 8, k = idx & 255;
        WTz[((k>>2)*512 + j)*4 + (k&3)] = Wihm[j*512 + k];
    }
    // packed recurrent weights [k2][j]
    for (int idx = g; idx < 64*512; idx += gs) {
        int k2 = idx >> 9, j = idx & 511;
        P0hh[idx] = pack2(pre0_Whh[j*128 + 2*k2], pre0_Whh[j*128 + 2*k2 + 1]);
        P1hh[idx] = pack2(pre1_Whh[j*128 + 2*k2], pre1_Whh[j*128 + 2*k2 + 1]);
        PMhh[idx] = pack2(Whhm[j*128 + 2*k2], Whhm[j*128 + 2*k2 + 1]);
    }
    for (int idx = g; idx < 64*256; idx += gs) {
        int k2 = idx >> 8, j = idx & 255;
        PMwh[idx] = pack2(Whm[j*128 + 2*k2], Whm[j*128 + 2*k2 + 1]);
    }
    // Wih_q stream: k = 256..511, layout [k4][512 j] of uint4 (8 halves)
    for (int idx = g; idx < 32*512; idx += gs) {
        int k4 = idx >> 9, j = idx & 511;
        int base = j*512 + 256 + 8*k4;
        PMwq[idx] = make_uint4(pack2(Wihm[base+0], Wihm[base+1]),
                               pack2(Wihm[base+2], Wihm[base+3]),
                               pack2(Wihm[base+4], Wihm[base+5]),
                               pack2(Wihm[base+6], Wihm[base+7]));
    }
}

// ---------- batched projection: C[t][b][j] = bias[j] + sum_k X[t][b][k]*W[j][k] ----------
// one block per time step; weight-stationary over 64 batches held in LDS (transposed)
template<int K, int M>
__global__ __launch_bounds__(M)
void proj_kernel(const float* __restrict__ X0, const float* __restrict__ W0,
                 const float* __restrict__ b0, float* __restrict__ C0, int T0,
                 const float* __restrict__ X1, const float* __restrict__ W1,
                 const float* __restrict__ b1, float* __restrict__ C1)
{
    __shared__ float Xs[K*68];
    int t = blockIdx.x;
    const float* X; const float* W; const float* bias; float* C; int trow;
    if (t < T0) { X = X0; W = W0; bias = b0; C = C0; trow = t; }
    else        { X = X1; W = W1; bias = b1; C = C1; trow = t - T0; }
    int j = threadIdx.x;
    for (int b = 0; b < 64; ++b) {
        for (int k = j; k < K; k += M)
            Xs[k*68 + b] = X[(trow*64 + b)*K + k];
    }
    __syncthreads();
    float acc[64];
    float binit = bias ? bias[j] : 0.f;
    #pragma unroll
    for (int b = 0; b < 64; ++b) acc[b] = binit;
    const float4* W4 = (const float4*)W;
    for (int k4 = 0; k4 < K/4; ++k4) {
        float4 w4 = W4[k4*M + j];
        float wv[4] = {w4.x, w4.y, w4.z, w4.w};
        #pragma unroll
        for (int kk = 0; kk < 4; ++kk) {
            int k = 4*k4 + kk;
            #pragma unroll
            for (int b4 = 0; b4 < 16; ++b4) {
                float4 x4 = *((const float4*)&Xs[k*68 + 4*b4]);
                acc[4*b4+0] = fmaf(wv[kk], x4.x, acc[4*b4+0]);
                acc[4*b4+1] = fmaf(wv[kk], x4.y, acc[4*b4+1]);
                acc[4*b4+2] = fmaf(wv[kk], x4.z, acc[4*b4+2]);
                acc[4*b4+3] = fmaf(wv[kk], x4.w, acc[4*b4+3]);
            }
        }
    }
    for (int b = 0; b < 64; ++b)
        C[(trow*64 + b)*M + j] = acc[b];
}

// ---------- pre-BiLSTM recurrence (quirk: cell h discarded; c masked; h = tanh(c)) ----------
// grid: 256 blocks. blocks 0..127: passage (b=bid>>1, dir=bid&1); 128..255: question.
// only gates i,f,g needed (o unused) -> 384 threads
__global__ __launch_bounds__(384)
void rec_pre_kernel(const float* __restrict__ Xp, const float* __restrict__ Xq,
                    const u32* __restrict__ Whh,
                    const float* __restrict__ mask_p, const float* __restrict__ mask_q,
                    float* __restrict__ Hp, float* __restrict__ Hq)
{
    int bid = blockIdx.x;
    int sub = bid & 127; int b = sub >> 1; int dir = sub & 1;
    const float* X; const float* mask; float* Hout; int T;
    if (bid < 128) { X = Xp; mask = mask_p; Hout = Hp; T = TP; }
    else           { X = Xq; mask = mask_q; Hout = Hq; T = TQ; }
    int j = threadIdx.x;
    __shared__ alignas(16) _Float16 h16[128];
    __shared__ float gates[384];
    u32 w[64];
    #pragma unroll
    for (int q = 0; q < 64; ++q) w[q] = Whh[q*512 + j];
    if (j < 128) h16[j] = (_Float16)0.f;
    float c = 0.f;
    __syncthreads();
    const uint4* h4p = (const uint4*)h16;
    for (int s = 0; s < T; ++s) {
        int ti = dir ? (T-1-s) : s;
        float acc = X[(ti*64 + b)*512 + j];
        #pragma unroll
        for (int q4 = 0; q4 < 16; ++q4) {
            uint4 hv = h4p[q4];
            acc = dot2x(w[q4*4+0], hv.x, acc);
            acc = dot2x(w[q4*4+1], hv.y, acc);
            acc = dot2x(w[q4*4+2], hv.z, acc);
            acc = dot2x(w[q4*4+3], hv.w, acc);
        }
        gates[j] = acc;
        __syncthreads();
        if (j < 128) {
            float gi = gates[j], gf = gates[128+j], gg = gates[256+j];
            float m = mask[ti*64 + b];
            c = sigm_fast(gf)*c + sigm_fast(gi)*tanh_fast(gg);
            c *= m;
            float h = tanh_fast(c);
            h16[j] = (_Float16)h;
            Hout[(ti*64 + b)*256 + dir*128 + j] = h;
        }
        __syncthreads();
    }
}

// ---------- Match-LSTM recurrence: one block per (b, dir) ----------
__global__ __launch_bounds__(512)
void match_kernel(const float* __restrict__ ap,   // [600][64][256] = Hp1@Wp.T + bp
                  const float* __restrict__ aq,   // [60][64][256]  = Hq1@Wq.T
                  const float* __restrict__ Zp,   // [600][64][512] = Hp1@Wih[:, :256].T + b
                  const float* __restrict__ Hq1,  // [60][64][256]
                  const float* __restrict__ Wa,   // [256]
                  const float* __restrict__ mask_p,
                  const u32* __restrict__ PMwh,   // [64][256] packed Wh
                  const u32* __restrict__ PMhh,   // [64][512] packed Whh
                  const uint4* __restrict__ PMwq, // [32][512] packed Wih[:,256:]
                  float* __restrict__ out)        // [600][64][256]
{
    int bid = blockIdx.x; int b = bid >> 1; int dir = bid & 1;
    int tid = threadIdx.x;
    __shared__ float aqs[60*260];
    __shared__ alignas(16) _Float16 hqs[60*264];
    __shared__ float sumt[256];
    __shared__ float wa_s[256];
    __shared__ float score_s[64];
    __shared__ float alpha_s[64];
    __shared__ alignas(16) _Float16 wq16[256];
    __shared__ alignas(16) _Float16 h16[128];
    __shared__ float gates[512];

    for (int idx = tid; idx < 60*256; idx += 512) {
        int tq = idx >> 8, h = idx & 255;
        aqs[tq*260 + h] = aq[(tq*64 + b)*256 + h];
        hqs[tq*264 + h] = (_Float16)Hq1[(tq*64 + b)*256 + h];
    }
    if (tid < 256) wa_s[tid] = Wa[tid];
    if (tid < 128) h16[tid] = (_Float16)0.f;
    u32 wh[64], whh[64];
    #pragma unroll
    for (int q = 0; q < 64; ++q) whh[q] = PMhh[q*512 + tid];
    {
        int jw = tid & 255;
        #pragma unroll
        for (int q = 0; q < 64; ++q) wh[q] = PMwh[q*256 + jw];
    }
    float c = 0.f;
    __syncthreads();
    const uint4* h4p  = (const uint4*)h16;
    const uint4* wq4p = (const uint4*)wq16;

    for (int s = 0; s < TP; ++s) {
        int ti = dir ? (TP-1-s) : s;
        // 1. sumt = ap_t + h @ Wh.T
        if (tid < 256) {
            float acc = ap[(ti*64 + b)*256 + tid];
            #pragma unroll
            for (int q4 = 0; q4 < 16; ++q4) {
                uint4 hv = h4p[q4];
                acc = dot2x(wh[q4*4+0], hv.x, acc);
                acc = dot2x(wh[q4*4+1], hv.y, acc);
                acc = dot2x(wh[q4*4+2], hv.z, acc);
                acc = dot2x(wh[q4*4+3], hv.w, acc);
            }
            sumt[tid] = acc;
        }
        __syncthreads();
        // 2. scores: 8 threads per tq, interleaved h = sub + 8*i (bank-friendly)
        {
            int tq = tid >> 3, sb = tid & 7;
            float part = 0.f;
            if (tq < 60) {
                #pragma unroll 8
                for (int i = 0; i < 32; ++i) {
                    int h = sb + 8*i;
                    float g = tanh_fast(aqs[tq*260 + h] + sumt[h]);
                    part = fmaf(wa_s[h], g, part);
                }
            }
            part += __shfl_xor(part, 1);
            part += __shfl_xor(part, 2);
            part += __shfl_xor(part, 4);
            if (tq < 60 && sb == 0) score_s[tq] = part;
        }
        __syncthreads();
        // 3. softmax over TQ (wave 0); ba is softmax-invariant, skipped
        if (tid < 64) {
            float sc = (tid < 60) ? score_s[tid] : -3.0e38f;
            float m = sc;
            #pragma unroll
            for (int o = 32; o >= 1; o >>= 1) m = fmaxf(m, __shfl_xor(m, o));
            float e = (tid < 60) ? exp2_fast((sc - m) * 1.44269504f) : 0.f;
            float ssum = e;
            #pragma unroll
            for (int o = 32; o >= 1; o >>= 1) ssum += __shfl_xor(ssum, o);
            if (tid < 60) alpha_s[tid] = e * rcp_fast(ssum);
        }
        __syncthreads();
        // 4. wHq = sum_tq alpha[tq] * Hq[tq, :]
        if (tid < 256) {
            float acc = 0.f;
            #pragma unroll 6
            for (int tq = 0; tq < 60; ++tq)
                acc = fmaf(alpha_s[tq], (float)hqs[tq*264 + tid], acc);
            wq16[tid] = (_Float16)acc;
        }
        __syncthreads();
        // 5. gates = Zp_row + wHq @ Wih[:,256:].T + h @ Whh.T
        {
            float acc = Zp[(ti*64 + b)*512 + tid];
            #pragma unroll 8
            for (int q = 0; q < 32; ++q) {
                uint4 w4 = PMwq[q*512 + tid];
                uint4 xv = wq4p[q];
                acc = dot2x(w4.x, xv.x, acc);
                acc = dot2x(w4.y, xv.y, acc);
                acc = dot2x(w4.z, xv.z, acc);
                acc = dot2x(w4.w, xv.w, acc);
            }
            #pragma unroll
            for (int q4 = 0; q4 < 16; ++q4) {
                uint4 hv = h4p[q4];
                acc = dot2x(whh[q4*4+0], hv.x, acc);
                acc = dot2x(whh[q4*4+1], hv.y, acc);
                acc = dot2x(whh[q4*4+2], hv.z, acc);
                acc = dot2x(whh[q4*4+3], hv.w, acc);
            }
            gates[tid] = acc;
        }
        __syncthreads();
        // 6. full LSTM cell; h and c masked AFTER cell
        if (tid < 128) {
            float gi = gates[tid], gf = gates[128+tid], gg = gates[256+tid], go = gates[384+tid];
            c = sigm_fast(gf)*c + sigm_fast(gi)*tanh_fast(gg);
            float h = sigm_fast(go)*tanh_fast(c);
            float m = mask_p[ti*64 + b];
            h *= m; c *= m;
            h16[tid] = (_Float16)h;
            out[(ti*64 + b)*256 + dir*128 + tid] = h;
        }
        __syncthreads();
    }
}

// ---------- workspace layout (floats) ----------
#define O_BUFX   0UL          // 19,660,800  Xp0 -> Xp1 -> Zp
#define O_BUFXQ  19660800UL   //  1,966,080  Xq0 -> Xq1
#define O_HP0    21626880UL   //  9,830,400  Hp0 -> ap
#define O_HQ0    31457280UL   //    983,040  Hq0 -> aq
#define O_HP1    32440320UL   //  9,830,400
#define O_HQ1    42270720UL   //    983,040
#define O_WT0    43253760UL   //    176,128
#define O_WT1    43429888UL   //    131,072
#define O_WTQ    43560960UL   //     65,536
#define O_WTP    43626496UL   //     65,536
#define O_WTZ    43692032UL   //    131,072
#define O_P0HH   43823104UL   //     32,768 u32
#define O_P1HH   43855872UL
#define O_PMHH   43888640UL
#define O_PMWH   43921408UL   //     16,384 u32
#define O_PMWQ   43937792UL   //     65,536 u32
// total: 44,003,328 floats = ~176 MB

extern "C" void kernel_launch(void* const* d_in, const int* in_sizes, int n_in,
                              void* d_out, int out_size, void* d_ws, size_t ws_size,
                              hipStream_t stream)
{
    const float* passage  = (const float*)d_in[0];
    const float* question = (const float*)d_in[1];
    const float* mask_p   = (const float*)d_in[2];
    const float* mask_q   = (const float*)d_in[3];
    const float* pre0_Wih = (const float*)d_in[4];
    const float* pre0_Whh = (const float*)d_in[5];
    const float* pre0_b   = (const float*)d_in[6];
    const float* pre1_Wih = (const float*)d_in[7];
    const float* pre1_Whh = (const float*)d_in[8];
    const float* pre1_b   = (const float*)d_in[9];
    const float* mq_Wq    = (const float*)d_in[10];
    const float* mq_Wp    = (const float*)d_in[11];
    const float* mq_bp    = (const float*)d_in[12];
    const float* mq_Wh    = (const float*)d_in[13];
    const float* mq_Wa    = (const float*)d_in[14];
    // d_in[15] = mq_ba: constant added pre-softmax -> invariant, skipped
    const float* mq_Wih   = (const float*)d_in[16];
    const float* mq_Whh   = (const float*)d_in[17];
    const float* mq_b     = (const float*)d_in[18];

    float* ws = (float*)d_ws;
    float* bufX  = ws + O_BUFX;
    float* bufXq = ws + O_BUFXQ;
    float* Hp0   = ws + O_HP0;
    float* Hq0   = ws + O_HQ0;
    float* Hp1   = ws + O_HP1;
    float* Hq1   = ws + O_HQ1;
    float* WT0   = ws + O_WT0;
    float* WT1   = ws + O_WT1;
    float* WTq   = ws + O_WTQ;
    float* WTp   = ws + O_WTP;
    float* WTz   = ws + O_WTZ;
    u32*   P0hh  = (u32*)(ws + O_P0HH);
    u32*   P1hh  = (u32*)(ws + O_P1HH);
    u32*   PMhh  = (u32*)(ws + O_PMHH);
    u32*   PMwh  = (u32*)(ws + O_PMWH);
    uint4* PMwq  = (uint4*)(ws + O_PMWQ);
    float* ap = Hp0;   // reuse: Hp0 dead after rec1
    float* aq = Hq0;
    float* Zp = bufX;  // reuse: Xp1 dead after rec1

    prep_kernel<<<688, 256, 0, stream>>>(pre0_Wih, pre0_Whh, pre1_Wih, pre1_Whh,
                                         mq_Wq, mq_Wp, mq_Wh, mq_Wih, mq_Whh,
                                         WT0, WT1, WTq, WTp, WTz,
                                         P0hh, P1hh, PMhh, PMwh, PMwq);
    // pre0 input projections (passage + question fused)
    proj_kernel<EMB, 512><<<660, 512, 0, stream>>>(passage, WT0, pre0_b, bufX, TP,
                                                   question, WT0, pre0_b, bufXq);
    rec_pre_kernel<<<256, 384, 0, stream>>>(bufX, bufXq, P0hh, mask_p, mask_q, Hp0, Hq0);
    // pre1
    proj_kernel<256, 512><<<660, 512, 0, stream>>>(Hp0, WT1, pre1_b, bufX, TP,
                                                   Hq0, WT1, pre1_b, bufXq);
    rec_pre_kernel<<<256, 384, 0, stream>>>(bufX, bufXq, P1hh, mask_p, mask_q, Hp1, Hq1);
    // match precompute: ap (with bias), aq (no bias)
    proj_kernel<256, 256><<<660, 256, 0, stream>>>(Hp1, WTp, mq_bp, ap, TP,
                                                   Hq1, WTq, nullptr, aq);
    // Zp = Hp1 @ Wih[:, :256].T + mq_b
    proj_kernel<256, 512><<<600, 512, 0, stream>>>(Hp1, WTz, mq_b, Zp, TP,
                                                   nullptr, nullptr, nullptr, nullptr);
    // match recurrence: 64 batches x 2 directions
    match_kernel<<<128, 512, 0, stream>>>(ap, aq, Zp, Hq1, mq_Wa, mask_p,
                                          PMwh, PMhh, PMwq, (float*)d_out);
}

// Round 2
// 8485.854 us; speedup vs baseline: 1.3998x; 1.3998x over previous
//
#include <hip/hip_runtime.h>

typedef unsigned int u32;
typedef _Float16 f16x2 __attribute__((ext_vector_type(2)));

#define TP 600
#define TQ 60
#define BB 64
#define EMB 344
#define HH 256
#define H2 128
#define GG 512

// ---------- fast math helpers ----------
__device__ __forceinline__ float exp2_fast(float x){
#if __has_builtin(__builtin_amdgcn_exp2f)
    return __builtin_amdgcn_exp2f(x);
#else
    return exp2f(x);
#endif
}
__device__ __forceinline__ float rcp_fast(float x){
#if __has_builtin(__builtin_amdgcn_rcpf)
    return __builtin_amdgcn_rcpf(x);
#else
    return 1.0f / x;
#endif
}
__device__ __forceinline__ float sigm_fast(float x){
    return rcp_fast(1.f + exp2_fast(-1.44269504f * x));
}
__device__ __forceinline__ float tanh_fast(float x){
    return 1.f - 2.f * rcp_fast(1.f + exp2_fast(2.88539008f * x));
}
__device__ __forceinline__ float dot2x(u32 w, u32 h, float acc){
    f16x2 wv = __builtin_bit_cast(f16x2, w);
    f16x2 hv = __builtin_bit_cast(f16x2, h);
    acc = fmaf((float)wv.x, (float)hv.x, acc);
    acc = fmaf((float)wv.y, (float)hv.y, acc);
    return acc;
}
__device__ __forceinline__ u32 pack2(float a, float b){
    f16x2 v; v.x = (_Float16)a; v.y = (_Float16)b;
    return __builtin_bit_cast(u32, v);
}

// ---------- prep: transpose weights (fp32 WT4 layout) + fp16 packing ----------
__global__ void prep_kernel(const float* __restrict__ pre0_Wih, const float* __restrict__ pre0_Whh,
                            const float* __restrict__ pre1_Wih, const float* __restrict__ pre1_Whh,
                            const float* __restrict__ Wq, const float* __restrict__ Wp,
                            const float* __restrict__ Whm,
                            const float* __restrict__ Whhm,
                            float* __restrict__ WT0, float* __restrict__ WT1,
                            float* __restrict__ WTq, float* __restrict__ WTp,
                            float* __restrict__ WTz, const float* __restrict__ Wihm,
                            u32* __restrict__ P0hh, u32* __restrict__ P1hh,
                            u32* __restrict__ PMhh, u32* __restrict__ PMwh)
{
    int g = blockIdx.x * blockDim.x + threadIdx.x;
    int gs = gridDim.x * blockDim.x;
    // WT0: pre0_Wih [512][344] -> [k/4][512][4]
    for (int idx = g; idx < 512*344; idx += gs) {
        int j = idx / 344, k = idx - j*344;
        WT0[((k>>2)*512 + j)*4 + (k&3)] = pre0_Wih[idx];
    }
    // WT1: pre1_Wih [512][256]
    for (int idx = g; idx < 512*256; idx += gs) {
        int j = idx >> 8, k = idx & 255;
        WT1[((k>>2)*512 + j)*4 + (k&3)] = pre1_Wih[idx];
    }
    // WTq / WTp: [256][256]
    for (int idx = g; idx < 256*256; idx += gs) {
        int j = idx >> 8, k = idx & 255;
        WTq[((k>>2)*256 + j)*4 + (k&3)] = Wq[idx];
        WTp[((k>>2)*256 + j)*4 + (k&3)] = Wp[idx];
    }
    // WTz: mq_Wih[:, 0:256]
    for (int idx = g; idx < 512*256; idx += gs) {
        int j = idx >> 8, k = idx & 255;
        WTz[((k>>2)*512 + j)*4 + (k&3)] = Wihm[j*512 + k];
    }
    // packed recurrent weights [k2][j]
    for (int idx = g; idx < 64*512; idx += gs) {
        int k2 = idx >> 9, j = idx & 511;
        P0hh[idx] = pack2(pre0_Whh[j*128 + 2*k2], pre0_Whh[j*128 + 2*k2 + 1]);
        P1hh[idx] = pack2(pre1_Whh[j*128 + 2*k2], pre1_Whh[j*128 + 2*k2 + 1]);
        PMhh[idx] = pack2(Whhm[j*128 + 2*k2], Whhm[j*128 + 2*k2 + 1]);
    }
    for (int idx = g; idx < 64*256; idx += gs) {
        int k2 = idx >> 8, j = idx & 255;
        PMwh[idx] = pack2(Whm[j*128 + 2*k2], Whm[j*128 + 2*k2 + 1]);
    }
}

// ---------- batched projection: C[t][b][j] = bias[j] + sum_k X[t][b][k]*W[j][k] ----------
template<int K, int M>
__global__ __launch_bounds__(M)
void proj_kernel(const float* __restrict__ X0, const float* __restrict__ W0,
                 const float* __restrict__ b0, float* __restrict__ C0, int T0,
                 const float* __restrict__ X1, const float* __restrict__ W1,
                 const float* __restrict__ b1, float* __restrict__ C1)
{
    __shared__ float Xs[K*68];
    int t = blockIdx.x;
    const float* X; const float* W; const float* bias; float* C; int trow;
    if (t < T0) { X = X0; W = W0; bias = b0; C = C0; trow = t; }
    else        { X = X1; W = W1; bias = b1; C = C1; trow = t - T0; }
    int j = threadIdx.x;
    for (int b = 0; b < 64; ++b) {
        for (int k = j; k < K; k += M)
            Xs[k*68 + b] = X[(trow*64 + b)*K + k];
    }
    __syncthreads();
    float acc[64];
    float binit = bias ? bias[j] : 0.f;
    #pragma unroll
    for (int b = 0; b < 64; ++b) acc[b] = binit;
    const float4* W4 = (const float4*)W;
    for (int k4 = 0; k4 < K/4; ++k4) {
        float4 w4 = W4[k4*M + j];
        float wv[4] = {w4.x, w4.y, w4.z, w4.w};
        #pragma unroll
        for (int kk = 0; kk < 4; ++kk) {
            int k = 4*k4 + kk;
            #pragma unroll
            for (int b4 = 0; b4 < 16; ++b4) {
                float4 x4 = *((const float4*)&Xs[k*68 + 4*b4]);
                acc[4*b4+0] = fmaf(wv[kk], x4.x, acc[4*b4+0]);
                acc[4*b4+1] = fmaf(wv[kk], x4.y, acc[4*b4+1]);
                acc[4*b4+2] = fmaf(wv[kk], x4.z, acc[4*b4+2]);
                acc[4*b4+3] = fmaf(wv[kk], x4.w, acc[4*b4+3]);
            }
        }
    }
    for (int b = 0; b < 64; ++b)
        C[(trow*64 + b)*M + j] = acc[b];
}

// ---------- Yq precompute: Yq[tq][b][j] = sum_k Hq1[tq,b,k] * Wihm[j][256+k] ----------
__global__ __launch_bounds__(512)
void yq_kernel(const float* __restrict__ Hq1, const float* __restrict__ Wihm,
               float* __restrict__ Yq)
{
    __shared__ float Xs[256*68];
    int tq = blockIdx.x;
    int j = threadIdx.x;
    for (int b = 0; b < 64; ++b) {
        for (int k = j; k < 256; k += 512)
            Xs[k*68 + b] = Hq1[(tq*64 + b)*256 + k];
    }
    __syncthreads();
    float acc[64];
    #pragma unroll
    for (int b = 0; b < 64; ++b) acc[b] = 0.f;
    const float4* W4 = (const float4*)(Wihm + j*512 + 256);
    for (int k4 = 0; k4 < 64; ++k4) {
        float4 w4 = W4[k4];
        float wv[4] = {w4.x, w4.y, w4.z, w4.w};
        #pragma unroll
        for (int kk = 0; kk < 4; ++kk) {
            int k = 4*k4 + kk;
            #pragma unroll
            for (int b4 = 0; b4 < 16; ++b4) {
                float4 x4 = *((const float4*)&Xs[k*68 + 4*b4]);
                acc[4*b4+0] = fmaf(wv[kk], x4.x, acc[4*b4+0]);
                acc[4*b4+1] = fmaf(wv[kk], x4.y, acc[4*b4+1]);
                acc[4*b4+2] = fmaf(wv[kk], x4.z, acc[4*b4+2]);
                acc[4*b4+3] = fmaf(wv[kk], x4.w, acc[4*b4+3]);
            }
        }
    }
    for (int b = 0; b < 64; ++b)
        Yq[(tq*64 + b)*512 + j] = acc[b];
}

// ---------- pre-BiLSTM recurrence (h discarded; c masked; h = tanh(c)) ----------
__global__ __launch_bounds__(384)
void rec_pre_kernel(const float* __restrict__ Xp, const float* __restrict__ Xq,
                    const u32* __restrict__ Whh,
                    const float* __restrict__ mask_p, const float* __restrict__ mask_q,
                    float* __restrict__ Hp, float* __restrict__ Hq)
{
    int bid = blockIdx.x;
    int sub = bid & 127; int b = sub >> 1; int dir = sub & 1;
    const float* X; const float* mask; float* Hout; int T;
    if (bid < 128) { X = Xp; mask = mask_p; Hout = Hp; T = TP; }
    else           { X = Xq; mask = mask_q; Hout = Hq; T = TQ; }
    int j = threadIdx.x;
    __shared__ __align__(16) _Float16 h16[128];
    __shared__ float gates[384];
    u32 w[64];
    #pragma unroll
    for (int q = 0; q < 64; ++q) w[q] = Whh[q*512 + j];
    if (j < 128) h16[j] = (_Float16)0.f;
    float c = 0.f;
    int ti0 = dir ? (T-1) : 0;
    float x_c = X[(ti0*64 + b)*512 + j];
    float m_c = mask[ti0*64 + b];
    __syncthreads();
    const uint4* h4p = (const uint4*)h16;
    for (int s = 0; s < T; ++s) {
        int ti = dir ? (T-1-s) : s;
        int s1 = (s+1 < T) ? (s+1) : s;
        int tn = dir ? (T-1-s1) : s1;
        float x_n = X[(tn*64 + b)*512 + j];          // prefetch (HBM latency off path)
        float m_n = mask[tn*64 + b];
        float acc = x_c;
        #pragma unroll
        for (int q4 = 0; q4 < 16; ++q4) {
            uint4 hv = h4p[q4];
            acc = dot2x(w[q4*4+0], hv.x, acc);
            acc = dot2x(w[q4*4+1], hv.y, acc);
            acc = dot2x(w[q4*4+2], hv.z, acc);
            acc = dot2x(w[q4*4+3], hv.w, acc);
        }
        gates[j] = acc;
        __syncthreads();
        if (j < 128) {
            float gi = gates[j], gf = gates[128+j], gg = gates[256+j];
            c = sigm_fast(gf)*c + sigm_fast(gi)*tanh_fast(gg);
            c *= m_c;
            float h = tanh_fast(c);
            h16[j] = (_Float16)h;
            Hout[(ti*64 + b)*256 + dir*128 + j] = h;
        }
        __syncthreads();
        x_c = x_n; m_c = m_n;
    }
}

// ---------- Match-LSTM recurrence: one block per (b, dir) ----------
__global__ __launch_bounds__(512, 2)
void match_kernel(const float* __restrict__ ap,   // [600][64][256]
                  const float* __restrict__ aqg,  // [60][64][256]
                  const float* __restrict__ Zp,   // [600][64][512]
                  const float* __restrict__ Yq,   // [60][64][512]
                  const float* __restrict__ Wa,   // [256]
                  const float* __restrict__ mask_p,
                  const u32* __restrict__ PMwh,   // [64][256] packed Wh
                  const u32* __restrict__ PMhh,   // [64][512] packed Whh
                  float* __restrict__ out)        // [600][64][256]
{
    int bid = blockIdx.x; int b = bid >> 1; int dir = bid & 1;
    int tid = threadIdx.x;
    __shared__ __align__(16) u32 aq2[60*133];        // fp16 pairs of aq, odd stride
    __shared__ __align__(16) _Float16 Yq_s[512*68];  // row j: 68 halves (34 u32, 2-way-free)
    __shared__ __align__(16) float sumt[258];
    __shared__ __align__(16) float wa_s[258];
    __shared__ float score_s[64];
    __shared__ __align__(16) u32 alpha2_s[32];       // fp16 alpha pairs
    __shared__ __align__(16) _Float16 h16[128];
    __shared__ float gates[512];

    // stage aq as fp16 pairs
    for (int idx = tid; idx < 60*128; idx += 512) {
        int tq = idx >> 7, h2 = idx & 127;
        float2 a = *(const float2*)&aqg[(tq*64 + b)*256 + 2*h2];
        aq2[tq*133 + h2] = pack2(a.x, a.y);
    }
    // stage Yq transposed -> fp16, row stride 68
    for (int tq = 0; tq < 60; ++tq)
        Yq_s[tid*68 + tq] = (_Float16)Yq[(tq*64 + b)*512 + tid];
    #pragma unroll
    for (int tq = 60; tq < 64; ++tq) Yq_s[tid*68 + tq] = (_Float16)0.f;
    if (tid < 256) wa_s[tid] = Wa[tid];
    if (tid < 128) h16[tid] = (_Float16)0.f;

    u32 whh[64];
    #pragma unroll
    for (int q = 0; q < 64; ++q) whh[q] = PMhh[q*512 + tid];
    u32 wh[64];
    {
        int jw = tid & 255;
        #pragma unroll
        for (int q = 0; q < 64; ++q) wh[q] = PMwh[q*256 + jw];
    }
    float c = 0.f;
    int ti0 = dir ? (TP-1) : 0;
    float zp_c = Zp[(ti0*64 + b)*512 + tid];
    float ap_c = (tid < 256) ? ap[(ti0*64 + b)*256 + tid] : 0.f;
    float m_c  = mask_p[ti0*64 + b];
    __syncthreads();

    const uint4* h4p = (const uint4*)h16;
    const uint4* a4  = (const uint4*)alpha2_s;
    const uint2* yrow2 = (const uint2*)(Yq_s + (size_t)tid*68);

    for (int s = 0; s < TP; ++s) {
        int ti = dir ? (TP-1-s) : s;
        int s1 = (s+1 < TP) ? (s+1) : s;
        int tn = dir ? (TP-1-s1) : s1;
        // prefetch next step's rows (consumed one step later)
        float zp_n = Zp[(tn*64 + b)*512 + tid];
        float ap_n = (tid < 256) ? ap[(tn*64 + b)*256 + tid] : 0.f;
        float m_n  = mask_p[tn*64 + b];

        // P1: sumt = ap_t + h @ Wh.T   (uniform-broadcast LDS reads of h)
        if (tid < 256) {
            float acc = ap_c;
            #pragma unroll
            for (int q4 = 0; q4 < 16; ++q4) {
                uint4 hv = h4p[q4];
                acc = dot2x(wh[q4*4+0], hv.x, acc);
                acc = dot2x(wh[q4*4+1], hv.y, acc);
                acc = dot2x(wh[q4*4+2], hv.z, acc);
                acc = dot2x(wh[q4*4+3], hv.w, acc);
            }
            sumt[tid] = acc;
        }
        __syncthreads();
        // P2: scores[tq] = sum_h wa[h]*tanh(aq[tq,h]+sumt[h]); 8 threads per tq
        {
            int tq = tid >> 3, sb = tid & 7;
            float part = 0.f;
            if (tq < 60) {
                #pragma unroll
                for (int i = 0; i < 16; ++i) {
                    int h2 = sb + 8*i;
                    u32 apair = aq2[tq*133 + h2];
                    f16x2 av = __builtin_bit_cast(f16x2, apair);
                    float2 st = *(const float2*)&sumt[2*h2];   // broadcast
                    float2 wv = *(const float2*)&wa_s[2*h2];   // broadcast
                    part = fmaf(wv.x, tanh_fast((float)av.x + st.x), part);
                    part = fmaf(wv.y, tanh_fast((float)av.y + st.y), part);
                }
            }
            part += __shfl_xor(part, 1);
            part += __shfl_xor(part, 2);
            part += __shfl_xor(part, 4);
            if (tq < 60 && sb == 0) score_s[tq] = part;
        }
        __syncthreads();
        // P3: softmax over TQ on wave 0; pack alpha to fp16 pairs
        if (tid < 64) {
            float sc = (tid < 60) ? score_s[tid] : -3.0e38f;
            float m = sc;
            #pragma unroll
            for (int o = 32; o >= 1; o >>= 1) m = fmaxf(m, __shfl_xor(m, o));
            float e = (tid < 60) ? exp2_fast((sc - m) * 1.44269504f) : 0.f;
            float ssum = e;
            #pragma unroll
            for (int o = 32; o >= 1; o >>= 1) ssum += __shfl_xor(ssum, o);
            float al = e * rcp_fast(ssum);
            float a0 = __shfl(al, 2*tid);
            float a1 = __shfl(al, 2*tid + 1);
            if (tid < 32) alpha2_s[tid] = pack2(a0, a1);
        }
        __syncthreads();
        // P4: gates = Zp + sum_tq alpha[tq]*Yq_s[j][tq] + h @ Whh.T
        {
            float acc = zp_c;
            #pragma unroll
            for (int r = 0; r < 8; ++r) {
                uint4 av = a4[r];                 // uniform broadcast
                uint2 ya = yrow2[2*r + 0];        // 2-way (free) b64 reads
                uint2 yb = yrow2[2*r + 1];
                acc = dot2x(ya.x, av.x, acc);
                acc = dot2x(ya.y, av.y, acc);
                acc = dot2x(yb.x, av.z, acc);
                acc = dot2x(yb.y, av.w, acc);
            }
            #pragma unroll
            for (int q4 = 0; q4 < 16; ++q4) {
                uint4 hv = h4p[q4];
                acc = dot2x(whh[q4*4+0], hv.x, acc);
                acc = dot2x(whh[q4*4+1], hv.y, acc);
                acc = dot2x(whh[q4*4+2], hv.z, acc);
                acc = dot2x(whh[q4*4+3], hv.w, acc);
            }
            gates[tid] = acc;
        }
        __syncthreads();
        // P5: LSTM cell; h and c masked after cell
        if (tid < 128) {
            float gi = gates[tid], gf = gates[128+tid], gg = gates[256+tid], go = gates[384+tid];
            c = sigm_fast(gf)*c + sigm_fast(gi)*tanh_fast(gg);
            float h = sigm_fast(go)*tanh_fast(c);
            h *= m_c; c *= m_c;
            h16[tid] = (_Float16)h;
            out[(ti*64 + b)*256 + dir*128 + tid] = h;
        }
        __syncthreads();
        zp_c = zp_n; ap_c = ap_n; m_c = m_n;
    }
}

// ---------- workspace layout (floats) ----------
#define O_BUFX   0UL          // 19,660,800  Xp0 -> Xp1 -> Zp
#define O_BUFXQ  19660800UL   //  1,966,080  Xq0 -> Xq1 -> Yq
#define O_HP0    21626880UL   //  9,830,400  Hp0 -> ap
#define O_HQ0    31457280UL   //    983,040  Hq0 -> aq
#define O_HP1    32440320UL   //  9,830,400
#define O_HQ1    42270720UL   //    983,040
#define O_WT0    43253760UL   //    176,128
#define O_WT1    43429888UL   //    131,072
#define O_WTQ    43560960UL   //     65,536
#define O_WTP    43626496UL   //     65,536
#define O_WTZ    43692032UL   //    131,072
#define O_P0HH   43823104UL   //     32,768 u32
#define O_P1HH   43855872UL
#define O_PMHH   43888640UL
#define O_PMWH   43921408UL   //     16,384 u32
// total: 43,937,792 floats (~175.8 MB) — strictly within round-1 footprint

extern "C" void kernel_launch(void* const* d_in, const int* in_sizes, int n_in,
                              void* d_out, int out_size, void* d_ws, size_t ws_size,
                              hipStream_t stream)
{
    const float* passage  = (const float*)d_in[0];
    const float* question = (const float*)d_in[1];
    const float* mask_p   = (const float*)d_in[2];
    const float* mask_q   = (const float*)d_in[3];
    const float* pre0_Wih = (const float*)d_in[4];
    const float* pre0_Whh = (const float*)d_in[5];
    const float* pre0_b   = (const float*)d_in[6];
    const float* pre1_Wih = (const float*)d_in[7];
    const float* pre1_Whh = (const float*)d_in[8];
    const float* pre1_b   = (const float*)d_in[9];
    const float* mq_Wq    = (const float*)d_in[10];
    const float* mq_Wp    = (const float*)d_in[11];
    const float* mq_bp    = (const float*)d_in[12];
    const float* mq_Wh    = (const float*)d_in[13];
    const float* mq_Wa    = (const float*)d_in[14];
    // d_in[15] = mq_ba: softmax-invariant, skipped
    const float* mq_Wih   = (const float*)d_in[16];
    const float* mq_Whh   = (const float*)d_in[17];
    const float* mq_b     = (const float*)d_in[18];

    float* ws = (float*)d_ws;
    float* bufX  = ws + O_BUFX;
    float* bufXq = ws + O_BUFXQ;
    float* Hp0   = ws + O_HP0;
    float* Hq0   = ws + O_HQ0;
    float* Hp1   = ws + O_HP1;
    float* Hq1   = ws + O_HQ1;
    float* WT0   = ws + O_WT0;
    float* WT1   = ws + O_WT1;
    float* WTq   = ws + O_WTQ;
    float* WTp   = ws + O_WTP;
    float* WTz   = ws + O_WTZ;
    u32*   P0hh  = (u32*)(ws + O_P0HH);
    u32*   P1hh  = (u32*)(ws + O_P1HH);
    u32*   PMhh  = (u32*)(ws + O_PMHH);
    u32*   PMwh  = (u32*)(ws + O_PMWH);
    float* ap = Hp0;   // Hp0 dead after proj1
    float* aq = Hq0;
    float* Zp = bufX;  // Xp1 dead after rec1
    float* Yq = bufXq; // Xq1 dead after rec1

    prep_kernel<<<688, 256, 0, stream>>>(pre0_Wih, pre0_Whh, pre1_Wih, pre1_Whh,
                                         mq_Wq, mq_Wp, mq_Wh, mq_Whh,
                                         WT0, WT1, WTq, WTp, WTz, mq_Wih,
                                         P0hh, P1hh, PMhh, PMwh);
    // pre0 input projections
    proj_kernel<EMB, 512><<<660, 512, 0, stream>>>(passage, WT0, pre0_b, bufX, TP,
                                                   question, WT0, pre0_b, bufXq);
    rec_pre_kernel<<<256, 384, 0, stream>>>(bufX, bufXq, P0hh, mask_p, mask_q, Hp0, Hq0);
    // pre1
    proj_kernel<256, 512><<<660, 512, 0, stream>>>(Hp0, WT1, pre1_b, bufX, TP,
                                                   Hq0, WT1, pre1_b, bufXq);
    rec_pre_kernel<<<256, 384, 0, stream>>>(bufX, bufXq, P1hh, mask_p, mask_q, Hp1, Hq1);
    // match precompute: ap (bias bp), aq (no bias)
    proj_kernel<256, 256><<<660, 256, 0, stream>>>(Hp1, WTp, mq_bp, ap, TP,
                                                   Hq1, WTq, nullptr, aq);
    // Zp = Hp1 @ Wih[:, :256].T + mq_b
    proj_kernel<256, 512><<<600, 512, 0, stream>>>(Hp1, WTz, mq_b, Zp, TP,
                                                   nullptr, nullptr, nullptr, nullptr);
    // Yq[tq][b][j] = Hq1[tq,b,:] . Wih[j, 256:]
    yq_kernel<<<60, 512, 0, stream>>>(Hq1, mq_Wih, Yq);
    // match recurrence
    match_kernel<<<128, 512, 0, stream>>>(ap, aq, Zp, Yq, mq_Wa, mask_p,
                                          PMwh, PMhh, (float*)d_out);
}